// Round 12
// baseline (280.950 us; speedup 1.0000x reference)
//
#include <hip/hip_runtime.h>
#include <hip/hip_fp16.h>

#define N_NODES 50000
#define N_EDGES 1600000
#define IN_DIM  128
#define OUT_DIM 32
#define HEADS   4
#define EDGE_DIM 16

#define NB   512                 // dst buckets
#define DPB  98                  // dsts per bucket (512*98 = 50176 >= 50000)
#define CAP  4352                // records per bucket incl. pad (mean ~3892, +7.8 sigma)
#define SC_CHUNK 1024            // edges per scatter block (grid 1563 = ~6 blocks/CU)
#define SC_EPT   4               // 1024/256

// K1: h = x @ W^T (32-node tile); epilogue computes a_src/a_dst via
// wave-shuffle reduction and emits fp16 transposed h2t[n][d][head].
__global__ __launch_bounds__(256) void k_gemm(
    const float* __restrict__ x, const float* __restrict__ Wl,
    const float* __restrict__ att_src, const float* __restrict__ att_dst,
    __half* __restrict__ h2t, float* __restrict__ a_src,
    float* __restrict__ a_dst) {
  __shared__ float Wt[IN_DIM][68];
  __shared__ float xs[32][132];
  __shared__ float attS[IN_DIM], attD[IN_DIM];
  __shared__ float sred_s[32][4], sred_d[32][4];
  const int t = threadIdx.x;
  const int n0 = blockIdx.x * 32;

  if (t < IN_DIM) { attS[t] = att_src[t]; attD[t] = att_dst[t]; }

  for (int it = 0; it < 16; ++it) {
    int idx = it * 256 + t;
    int node = idx >> 7, i = idx & 127;
    int n = n0 + node;
    xs[node][i] = (n < N_NODES) ? x[(size_t)n * IN_DIM + i] : 0.f;
  }

  const int tx = t & 15, ty = t >> 4;
  const int na = n0 + 2 * ty, nb = na + 1;

  for (int p = 0; p < 2; ++p) {
    __syncthreads();
    for (int it = 0; it < 32; ++it) {
      int idx = it * 256 + t;
      int kg = (idx >> 7) + p * 64, i = idx & 127;
      Wt[i][kg - p * 64] = Wl[(size_t)kg * IN_DIM + i];
    }
    __syncthreads();

    float4 acc0 = {0.f,0.f,0.f,0.f}, acc1 = {0.f,0.f,0.f,0.f};
    for (int i4 = 0; i4 < IN_DIM; i4 += 4) {
      float4 xa = *(const float4*)&xs[2*ty][i4];
      float4 xb = *(const float4*)&xs[2*ty+1][i4];
      const float* xap = (const float*)&xa;
      const float* xbp = (const float*)&xb;
      #pragma unroll
      for (int ii = 0; ii < 4; ++ii) {
        float4 wv = *(const float4*)&Wt[i4+ii][tx*4];
        float a = xap[ii], b = xbp[ii];
        acc0.x += a*wv.x; acc0.y += a*wv.y; acc0.z += a*wv.z; acc0.w += a*wv.w;
        acc1.x += b*wv.x; acc1.y += b*wv.y; acc1.z += b*wv.z; acc1.w += b*wv.w;
      }
    }
    const int k = p*64 + tx*4;
    const int hd = k >> 5, d0 = k & 31;
    const float* ap = (const float*)&acc0;
    const float* bp = (const float*)&acc1;

    float sa = ap[0]*attS[k] + ap[1]*attS[k+1] + ap[2]*attS[k+2] + ap[3]*attS[k+3];
    float da = ap[0]*attD[k] + ap[1]*attD[k+1] + ap[2]*attD[k+2] + ap[3]*attD[k+3];
    float sb = bp[0]*attS[k] + bp[1]*attS[k+1] + bp[2]*attS[k+2] + bp[3]*attS[k+3];
    float db = bp[0]*attD[k] + bp[1]*attD[k+1] + bp[2]*attD[k+2] + bp[3]*attD[k+3];
    #pragma unroll
    for (int off = 1; off <= 4; off <<= 1) {
      sa += __shfl_xor(sa, off); da += __shfl_xor(da, off);
      sb += __shfl_xor(sb, off); db += __shfl_xor(db, off);
    }
    if ((tx & 7) == 0) {
      sred_s[2*ty][hd] = sa; sred_s[2*ty+1][hd] = sb;
      sred_d[2*ty][hd] = da; sred_d[2*ty+1][hd] = db;
    }

    if (na < N_NODES) {
      #pragma unroll
      for (int j = 0; j < 4; ++j)
        h2t[(size_t)na*IN_DIM + (d0+j)*4 + hd] = __float2half(ap[j]);
    }
    if (nb < N_NODES) {
      #pragma unroll
      for (int j = 0; j < 4; ++j)
        h2t[(size_t)nb*IN_DIM + (d0+j)*4 + hd] = __float2half(bp[j]);
    }
  }
  __syncthreads();
  if (t < 128) {
    int node = t >> 2;
    if (n0 + node < N_NODES)
      a_src[(size_t)(n0 + node) * 4 + (t & 3)] = sred_s[node][t & 3];
  } else {
    int tt = t - 128, node = tt >> 2;
    if (n0 + node < N_NODES)
      a_dst[(size_t)(n0 + node) * 4 + (tt & 3)] = sred_d[node][tt & 3];
  }
}

// K2: fused edge logits -> p=exp(lg) + bucket scatter, staging-free.
// LDS histogram -> even-padded chunk reservation (32B-aligned bursts;
// zero-records pad odd counts, arithmetically inert) -> direct 16B writes.
__global__ __launch_bounds__(256) void k_scatter3(
    const int* __restrict__ ei, const float* __restrict__ eattr,
    const float* __restrict__ a_src, const float* __restrict__ a_dst,
    const float* __restrict__ W_edge, unsigned int* __restrict__ gcursor,
    float4* __restrict__ rec, unsigned char* __restrict__ rdl) {
  __shared__ float We[HEADS * EDGE_DIM];
  __shared__ unsigned int cntb[NB], gbase[NB];
  const int t = threadIdx.x;
  if (t < HEADS * EDGE_DIM) We[t] = W_edge[t];
  for (int i = t; i < NB; i += 256) cntb[i] = 0u;
  __syncthreads();

  const int base = blockIdx.x * SC_CHUNK;
  unsigned int rx[SC_EPT], ry[SC_EPT], rz[SC_EPT], rk[SC_EPT];
  int bk[SC_EPT]; unsigned char dl8[SC_EPT]; bool ok[SC_EPT];

  #pragma unroll
  for (int i = 0; i < SC_EPT; ++i) {
    int e = base + i * 256 + t;
    ok[i] = (e < N_EDGES);
    if (ok[i]) {
      int src = ei[e], dst = ei[N_EDGES + e];
      float asp[4], adp[4], ea[EDGE_DIM];
      *(float4*)asp = *(const float4*)(a_src + (size_t)src * 4);
      *(float4*)adp = *(const float4*)(a_dst + (size_t)dst * 4);
      #pragma unroll
      for (int j = 0; j < 4; ++j)
        *(float4*)&ea[j*4] = *(const float4*)(eattr + (size_t)e * EDGE_DIM + j*4);
      float pv[HEADS];
      #pragma unroll
      for (int hh = 0; hh < HEADS; ++hh) {
        float sum = asp[hh] + adp[hh];
        #pragma unroll
        for (int j = 0; j < EDGE_DIM; ++j) sum += ea[j] * We[hh*EDGE_DIM + j];
        float lg = (sum > 0.f) ? sum : 0.2f * sum;
        pv[hh] = __expf(lg);
      }
      __half2 p01 = __floats2half2_rn(pv[0], pv[1]);
      __half2 p23 = __floats2half2_rn(pv[2], pv[3]);
      int b = dst / DPB;
      bk[i] = b;
      dl8[i] = (unsigned char)(dst - b * DPB);
      rx[i] = *(const unsigned int*)&p01;
      ry[i] = *(const unsigned int*)&p23;
      rz[i] = (unsigned int)src;
      rk[i] = atomicAdd(&cntb[b], 1u);
    }
  }
  __syncthreads();

  // reserve even-sized contiguous chunk per touched bucket; write pad record
  for (int b = t; b < NB; b += 256) {
    unsigned int c = cntb[b];
    if (c) {
      unsigned int creq = (c + 1u) & ~1u;
      unsigned int gb = atomicAdd(&gcursor[b], creq);
      gbase[b] = gb;
      if (c & 1u) {  // zero-record pad: p=0 contributes nothing downstream
        float4 z = {0.f, 0.f, 0.f, 0.f};
        rec[(size_t)b * CAP + gb + c] = z;
        rdl[(size_t)b * CAP + gb + c] = 0;
      }
    }
  }
  __syncthreads();

  // direct writes into reserved ranges (32B-aligned bursts merge in L2)
  #pragma unroll
  for (int i = 0; i < SC_EPT; ++i) {
    if (ok[i]) {
      unsigned int pos = gbase[bk[i]] + rk[i];
      float4 r;
      r.x = __uint_as_float(rx[i]); r.y = __uint_as_float(ry[i]);
      r.z = __uint_as_float(rz[i]); r.w = __uint_as_float((unsigned int)dl8[i]);
      rec[(size_t)bk[i] * CAP + pos] = r;
      rdl[(size_t)bk[i] * CAP + pos] = dl8[i];
    }
  }
}

// K3: one 1024-thread block per bucket. u16 dst-sorted index from u8 dl,
// then wave-per-dst gather-accumulate (p already exponentiated).
__global__ __launch_bounds__(1024) void k_bagg(
    const unsigned int* __restrict__ gcursor, const float4* __restrict__ rec,
    const unsigned char* __restrict__ rdl, const __half* __restrict__ h2t,
    const float* __restrict__ bias, float* __restrict__ out) {
  __shared__ unsigned short idx[CAP];
  __shared__ unsigned int cnt[DPB], off[DPB], cnt2[DPB];
  const int t = threadIdx.x;
  const int b = blockIdx.x;
  const size_t base = (size_t)b * CAP;
  const unsigned int cntT = gcursor[b];

  for (int i = t; i < DPB; i += 1024) { cnt[i] = 0u; cnt2[i] = 0u; }
  __syncthreads();

  for (unsigned int j = t; j < cntT; j += 1024)
    atomicAdd(&cnt[rdl[base + j]], 1u);
  __syncthreads();
  if (t == 0) {
    unsigned int run = 0;
    for (int i = 0; i < DPB; ++i) { off[i] = run; run += cnt[i]; }
  }
  __syncthreads();
  for (unsigned int j = t; j < cntT; j += 1024) {
    int dl = rdl[base + j];
    unsigned int r = atomicAdd(&cnt2[dl], 1u);
    idx[off[dl] + r] = (unsigned short)j;
  }
  __syncthreads();

  const int wv = t >> 6, lane = t & 63, half_ = lane >> 5, dd = lane & 31;
  for (int dl = wv; dl < DPB; dl += 16) {
    int node = b * DPB + dl;
    if (node >= N_NODES) break;
    const unsigned int s0 = off[dl], c = cnt[dl];

    float acc0 = 0.f, acc1 = 0.f, acc2 = 0.f, acc3 = 0.f;
    float dn0 = 0.f, dn1 = 0.f, dn2 = 0.f, dn3 = 0.f;

    unsigned int j = half_;
    for (; j + 2 < c; j += 4) {
      float4 ra = rec[base + idx[s0 + j]];
      float4 rb = rec[base + idx[s0 + j + 2]];
      unsigned int a01 = __float_as_uint(ra.x), a23 = __float_as_uint(ra.y);
      unsigned int b01 = __float_as_uint(rb.x), b23 = __float_as_uint(rb.y);
      int sa = (int)__float_as_uint(ra.z), sb = (int)__float_as_uint(rb.z);
      uint2 hra = *(const uint2*)(h2t + (size_t)sa * IN_DIM + dd * 4);
      uint2 hrb = *(const uint2*)(h2t + (size_t)sb * IN_DIM + dd * 4);
      float2 pa01 = __half22float2(*(const __half2*)&a01);
      float2 pa23 = __half22float2(*(const __half2*)&a23);
      dn0 += pa01.x; dn1 += pa01.y; dn2 += pa23.x; dn3 += pa23.y;
      float2 ha01 = __half22float2(*(const __half2*)&hra.x);
      float2 ha23 = __half22float2(*(const __half2*)&hra.y);
      acc0 += pa01.x * ha01.x; acc1 += pa01.y * ha01.y;
      acc2 += pa23.x * ha23.x; acc3 += pa23.y * ha23.y;
      float2 pb01 = __half22float2(*(const __half2*)&b01);
      float2 pb23 = __half22float2(*(const __half2*)&b23);
      dn0 += pb01.x; dn1 += pb01.y; dn2 += pb23.x; dn3 += pb23.y;
      float2 hb01 = __half22float2(*(const __half2*)&hrb.x);
      float2 hb23 = __half22float2(*(const __half2*)&hrb.y);
      acc0 += pb01.x * hb01.x; acc1 += pb01.y * hb01.y;
      acc2 += pb23.x * hb23.x; acc3 += pb23.y * hb23.y;
    }
    for (; j < c; j += 2) {
      float4 r = rec[base + idx[s0 + j]];
      unsigned int u01 = __float_as_uint(r.x), u23 = __float_as_uint(r.y);
      int src = (int)__float_as_uint(r.z);
      uint2 raw = *(const uint2*)(h2t + (size_t)src * IN_DIM + dd * 4);
      float2 p01 = __half22float2(*(const __half2*)&u01);
      float2 p23 = __half22float2(*(const __half2*)&u23);
      dn0 += p01.x; dn1 += p01.y; dn2 += p23.x; dn3 += p23.y;
      float2 h01 = __half22float2(*(const __half2*)&raw.x);
      float2 h23 = __half22float2(*(const __half2*)&raw.y);
      acc0 += p01.x * h01.x; acc1 += p01.y * h01.y;
      acc2 += p23.x * h23.x; acc3 += p23.y * h23.y;
    }

    dn0 += __shfl_xor(dn0, 32); dn1 += __shfl_xor(dn1, 32);
    dn2 += __shfl_xor(dn2, 32); dn3 += __shfl_xor(dn3, 32);
    acc0 += __shfl_xor(acc0, 32); acc1 += __shfl_xor(acc1, 32);
    acc2 += __shfl_xor(acc2, 32); acc3 += __shfl_xor(acc3, 32);

    if (half_ == 0) {
      float v = acc0 * (0.25f / (dn0 + 1e-16f)) + acc1 * (0.25f / (dn1 + 1e-16f))
              + acc2 * (0.25f / (dn2 + 1e-16f)) + acc3 * (0.25f / (dn3 + 1e-16f));
      out[(size_t)node * OUT_DIM + dd] = v + bias[dd];
    }
  }
}

extern "C" void kernel_launch(void* const* d_in, const int* in_sizes, int n_in,
                              void* d_out, int out_size, void* d_ws, size_t ws_size,
                              hipStream_t stream) {
  const float* x       = (const float*)d_in[0];
  const int*   ei      = (const int*)d_in[1];
  const float* eattr   = (const float*)d_in[2];
  const float* W_lin   = (const float*)d_in[3];
  const float* att_src = (const float*)d_in[4];
  const float* att_dst = (const float*)d_in[5];
  const float* bias    = (const float*)d_in[6];
  const float* W_edge  = (const float*)d_in[7];
  float* out = (float*)d_out;

  // ws: h2t(12.8MB) | rec(512*4352*16B = 35.7MB) | rdl(2.2MB) | a_src | a_dst | gcursor
  __half* h2t  = (__half*)d_ws;
  float4* rec  = (float4*)(h2t + (size_t)N_NODES * IN_DIM);
  unsigned char* rdl = (unsigned char*)(rec + (size_t)NB * CAP);
  float* a_src = (float*)(rdl + (size_t)NB * CAP);
  float* a_dst = a_src + (size_t)N_NODES * HEADS;
  unsigned int* gcursor = (unsigned int*)(a_dst + (size_t)N_NODES * HEADS);

  hipMemsetAsync(gcursor, 0, NB * sizeof(unsigned int), stream);

  k_gemm<<<(N_NODES + 31) / 32, 256, 0, stream>>>(
      x, W_lin, att_src, att_dst, h2t, a_src, a_dst);
  k_scatter3<<<(N_EDGES + SC_CHUNK - 1) / SC_CHUNK, 256, 0, stream>>>(
      ei, eattr, a_src, a_dst, W_edge, gcursor, rec, rdl);
  k_bagg<<<NB, 1024, 0, stream>>>(gcursor, rec, rdl, h2t, bias, out);
}

// Round 13
// 163.086 us; speedup vs baseline: 1.7227x; 1.7227x over previous
//
#include <hip/hip_runtime.h>
#include <hip/hip_fp16.h>

#define N_NODES 50000
#define N_EDGES 1600000
#define IN_DIM  128
#define OUT_DIM 32
#define HEADS   4
#define EDGE_DIM 16

#define NB   512                 // dst buckets
#define DPB  98                  // dsts per bucket (512*98 = 50176 >= 50000)
#define CAP  4224                // records/bucket incl. pads (mean ~3903, +5.5 sigma)
#define SC_CHUNK 1024            // edges per scatter block (grid 1563, ~6 blocks/CU)
#define SC_EPT   4               // 1024/256
#define PAD_DL 255               // inert pad marker (skipped by bagg pass 3)

// K1: h = x @ W^T (32-node tile); epilogue computes a_src/a_dst via
// wave-shuffle reduction and emits fp16 transposed h2t[n][d][head].
__global__ __launch_bounds__(256) void k_gemm(
    const float* __restrict__ x, const float* __restrict__ Wl,
    const float* __restrict__ att_src, const float* __restrict__ att_dst,
    __half* __restrict__ h2t, float* __restrict__ a_src,
    float* __restrict__ a_dst) {
  __shared__ float Wt[IN_DIM][68];
  __shared__ float xs[32][132];
  __shared__ float attS[IN_DIM], attD[IN_DIM];
  __shared__ float sred_s[32][4], sred_d[32][4];
  const int t = threadIdx.x;
  const int n0 = blockIdx.x * 32;

  if (t < IN_DIM) { attS[t] = att_src[t]; attD[t] = att_dst[t]; }

  for (int it = 0; it < 16; ++it) {
    int idx = it * 256 + t;
    int node = idx >> 7, i = idx & 127;
    int n = n0 + node;
    xs[node][i] = (n < N_NODES) ? x[(size_t)n * IN_DIM + i] : 0.f;
  }

  const int tx = t & 15, ty = t >> 4;
  const int na = n0 + 2 * ty, nb = na + 1;

  for (int p = 0; p < 2; ++p) {
    __syncthreads();
    for (int it = 0; it < 32; ++it) {
      int idx = it * 256 + t;
      int kg = (idx >> 7) + p * 64, i = idx & 127;
      Wt[i][kg - p * 64] = Wl[(size_t)kg * IN_DIM + i];
    }
    __syncthreads();

    float4 acc0 = {0.f,0.f,0.f,0.f}, acc1 = {0.f,0.f,0.f,0.f};
    for (int i4 = 0; i4 < IN_DIM; i4 += 4) {
      float4 xa = *(const float4*)&xs[2*ty][i4];
      float4 xb = *(const float4*)&xs[2*ty+1][i4];
      const float* xap = (const float*)&xa;
      const float* xbp = (const float*)&xb;
      #pragma unroll
      for (int ii = 0; ii < 4; ++ii) {
        float4 wv = *(const float4*)&Wt[i4+ii][tx*4];
        float a = xap[ii], b = xbp[ii];
        acc0.x += a*wv.x; acc0.y += a*wv.y; acc0.z += a*wv.z; acc0.w += a*wv.w;
        acc1.x += b*wv.x; acc1.y += b*wv.y; acc1.z += b*wv.z; acc1.w += b*wv.w;
      }
    }
    const int k = p*64 + tx*4;
    const int hd = k >> 5, d0 = k & 31;
    const float* ap = (const float*)&acc0;
    const float* bp = (const float*)&acc1;

    float sa = ap[0]*attS[k] + ap[1]*attS[k+1] + ap[2]*attS[k+2] + ap[3]*attS[k+3];
    float da = ap[0]*attD[k] + ap[1]*attD[k+1] + ap[2]*attD[k+2] + ap[3]*attD[k+3];
    float sb = bp[0]*attS[k] + bp[1]*attS[k+1] + bp[2]*attS[k+2] + bp[3]*attS[k+3];
    float db = bp[0]*attD[k] + bp[1]*attD[k+1] + bp[2]*attD[k+2] + bp[3]*attD[k+3];
    #pragma unroll
    for (int off = 1; off <= 4; off <<= 1) {
      sa += __shfl_xor(sa, off); da += __shfl_xor(da, off);
      sb += __shfl_xor(sb, off); db += __shfl_xor(db, off);
    }
    if ((tx & 7) == 0) {
      sred_s[2*ty][hd] = sa; sred_s[2*ty+1][hd] = sb;
      sred_d[2*ty][hd] = da; sred_d[2*ty+1][hd] = db;
    }

    if (na < N_NODES) {
      #pragma unroll
      for (int j = 0; j < 4; ++j)
        h2t[(size_t)na*IN_DIM + (d0+j)*4 + hd] = __float2half(ap[j]);
    }
    if (nb < N_NODES) {
      #pragma unroll
      for (int j = 0; j < 4; ++j)
        h2t[(size_t)nb*IN_DIM + (d0+j)*4 + hd] = __float2half(bp[j]);
    }
  }
  __syncthreads();
  if (t < 128) {
    int node = t >> 2;
    if (n0 + node < N_NODES)
      a_src[(size_t)(n0 + node) * 4 + (t & 3)] = sred_s[node][t & 3];
  } else {
    int tt = t - 128, node = tt >> 2;
    if (n0 + node < N_NODES)
      a_dst[(size_t)(n0 + node) * 4 + (tt & 3)] = sred_d[node][tt & 3];
  }
}

// K2: fused edge logits -> p=exp(lg) + bucket scatter, staging-free.
// LDS histogram -> even-padded reservation (32B-aligned bursts; pad records
// carry dl=255 so bagg ignores them) -> direct 16B writes. No rdl byte array.
__global__ __launch_bounds__(256) void k_scatter3(
    const int* __restrict__ ei, const float* __restrict__ eattr,
    const float* __restrict__ a_src, const float* __restrict__ a_dst,
    const float* __restrict__ W_edge, unsigned int* __restrict__ gcursor,
    float4* __restrict__ rec) {
  __shared__ float We[HEADS * EDGE_DIM];
  __shared__ unsigned int cntb[NB], gbase[NB];
  const int t = threadIdx.x;
  if (t < HEADS * EDGE_DIM) We[t] = W_edge[t];
  for (int i = t; i < NB; i += 256) cntb[i] = 0u;
  __syncthreads();

  const int base = blockIdx.x * SC_CHUNK;
  unsigned int rx[SC_EPT], ry[SC_EPT], rz[SC_EPT], rk[SC_EPT];
  int bk[SC_EPT]; unsigned char dl8[SC_EPT]; bool ok[SC_EPT];

  #pragma unroll
  for (int i = 0; i < SC_EPT; ++i) {
    int e = base + i * 256 + t;
    ok[i] = (e < N_EDGES);
    if (ok[i]) {
      int src = ei[e], dst = ei[N_EDGES + e];
      float asp[4], adp[4], ea[EDGE_DIM];
      *(float4*)asp = *(const float4*)(a_src + (size_t)src * 4);
      *(float4*)adp = *(const float4*)(a_dst + (size_t)dst * 4);
      #pragma unroll
      for (int j = 0; j < 4; ++j)
        *(float4*)&ea[j*4] = *(const float4*)(eattr + (size_t)e * EDGE_DIM + j*4);
      float pv[HEADS];
      #pragma unroll
      for (int hh = 0; hh < HEADS; ++hh) {
        float sum = asp[hh] + adp[hh];
        #pragma unroll
        for (int j = 0; j < EDGE_DIM; ++j) sum += ea[j] * We[hh*EDGE_DIM + j];
        float lg = (sum > 0.f) ? sum : 0.2f * sum;
        pv[hh] = __expf(lg);
      }
      __half2 p01 = __floats2half2_rn(pv[0], pv[1]);
      __half2 p23 = __floats2half2_rn(pv[2], pv[3]);
      int b = dst / DPB;
      bk[i] = b;
      dl8[i] = (unsigned char)(dst - b * DPB);
      rx[i] = *(const unsigned int*)&p01;
      ry[i] = *(const unsigned int*)&p23;
      rz[i] = (unsigned int)src;
      rk[i] = atomicAdd(&cntb[b], 1u);
    }
  }
  __syncthreads();

  // reserve even-sized contiguous chunk per touched bucket; inert pad record
  for (int b = t; b < NB; b += 256) {
    unsigned int c = cntb[b];
    if (c) {
      unsigned int creq = (c + 1u) & ~1u;
      unsigned int gb = atomicAdd(&gcursor[b], creq);
      gbase[b] = gb;
      if ((c & 1u) && (gb + c < CAP)) {
        float4 z;
        z.x = 0.f; z.y = 0.f; z.z = 0.f;
        z.w = __uint_as_float((unsigned int)PAD_DL);   // skipped downstream
        rec[(size_t)b * CAP + gb + c] = z;
      }
    }
  }
  __syncthreads();

  // direct writes into reserved ranges (32B-aligned bursts merge in L2)
  #pragma unroll
  for (int i = 0; i < SC_EPT; ++i) {
    if (ok[i]) {
      unsigned int pos = gbase[bk[i]] + rk[i];
      if (pos < CAP) {
        float4 r;
        r.x = __uint_as_float(rx[i]); r.y = __uint_as_float(ry[i]);
        r.z = __uint_as_float(rz[i]); r.w = __uint_as_float((unsigned int)dl8[i]);
        rec[(size_t)bk[i] * CAP + pos] = r;
      }
    }
  }
}

// K3: one 1024-thread block per bucket (77KB LDS -> 2 blocks/CU, 32 waves).
// Pass 1: single coalesced read of the bucket's records into LDS srec,
// dl kept in registers + LDS histogram (256 entries; 255 = pad).
// Pass 2: build u16 sorted index from registers. Pass 3: wave-per-dst
// accumulate from LDS; only h2t reads go to global.
__global__ __launch_bounds__(1024) void k_bagg(
    const unsigned int* __restrict__ gcursor, const float4* __restrict__ rec,
    const __half* __restrict__ h2t, const float* __restrict__ bias,
    float* __restrict__ out) {
  __shared__ float4 srec[CAP];              // 66 KB
  __shared__ unsigned short idx[CAP];       // 8.25 KB
  __shared__ unsigned int cnt[256], off[256], cnt2[256];
  const int t = threadIdx.x;
  const int b = blockIdx.x;
  const size_t base = (size_t)b * CAP;
  unsigned int cntT = gcursor[b];
  if (cntT > CAP) cntT = CAP;

  if (t < 256) { cnt[t] = 0u; cnt2[t] = 0u; }
  __syncthreads();

  // pass 1: stage + histogram (dl kept in regs)
  int dl_r[5]; unsigned short jj[5]; int nmine = 0;
  for (unsigned int j = t; j < cntT; j += 1024) {
    float4 r = rec[base + j];
    srec[j] = r;
    int dl = (int)__float_as_uint(r.w);
    dl_r[nmine] = dl; jj[nmine] = (unsigned short)j; ++nmine;
    atomicAdd(&cnt[dl], 1u);
  }
  __syncthreads();
  if (t == 0) {
    unsigned int run = 0;
    for (int i = 0; i < 256; ++i) { off[i] = run; run += cnt[i]; }
  }
  __syncthreads();
  // pass 2: build index (skip pads)
  for (int k = 0; k < nmine; ++k) {
    int dl = dl_r[k];
    if (dl != PAD_DL) {
      unsigned int r = atomicAdd(&cnt2[dl], 1u);
      idx[off[dl] + r] = jj[k];
    }
  }
  __syncthreads();

  // pass 3: wave-per-dst, half-waves alternate records, 2-deep pipe
  const int wv = t >> 6, lane = t & 63, half_ = lane >> 5, dd = lane & 31;
  for (int dl = wv; dl < DPB; dl += 16) {
    int node = b * DPB + dl;
    if (node >= N_NODES) break;
    const unsigned int s0 = off[dl], c = cnt[dl];

    float acc0 = 0.f, acc1 = 0.f, acc2 = 0.f, acc3 = 0.f;
    float dn0 = 0.f, dn1 = 0.f, dn2 = 0.f, dn3 = 0.f;

    unsigned int j = half_;
    for (; j + 2 < c; j += 4) {
      float4 ra = srec[idx[s0 + j]];
      float4 rb = srec[idx[s0 + j + 2]];
      unsigned int a01 = __float_as_uint(ra.x), a23 = __float_as_uint(ra.y);
      unsigned int b01 = __float_as_uint(rb.x), b23 = __float_as_uint(rb.y);
      int sa = (int)__float_as_uint(ra.z), sb = (int)__float_as_uint(rb.z);
      uint2 hra = *(const uint2*)(h2t + (size_t)sa * IN_DIM + dd * 4);
      uint2 hrb = *(const uint2*)(h2t + (size_t)sb * IN_DIM + dd * 4);
      float2 pa01 = __half22float2(*(const __half2*)&a01);
      float2 pa23 = __half22float2(*(const __half2*)&a23);
      dn0 += pa01.x; dn1 += pa01.y; dn2 += pa23.x; dn3 += pa23.y;
      float2 ha01 = __half22float2(*(const __half2*)&hra.x);
      float2 ha23 = __half22float2(*(const __half2*)&hra.y);
      acc0 += pa01.x * ha01.x; acc1 += pa01.y * ha01.y;
      acc2 += pa23.x * ha23.x; acc3 += pa23.y * ha23.y;
      float2 pb01 = __half22float2(*(const __half2*)&b01);
      float2 pb23 = __half22float2(*(const __half2*)&b23);
      dn0 += pb01.x; dn1 += pb01.y; dn2 += pb23.x; dn3 += pb23.y;
      float2 hb01 = __half22float2(*(const __half2*)&hrb.x);
      float2 hb23 = __half22float2(*(const __half2*)&hrb.y);
      acc0 += pb01.x * hb01.x; acc1 += pb01.y * hb01.y;
      acc2 += pb23.x * hb23.x; acc3 += pb23.y * hb23.y;
    }
    for (; j < c; j += 2) {
      float4 r = srec[idx[s0 + j]];
      unsigned int u01 = __float_as_uint(r.x), u23 = __float_as_uint(r.y);
      int src = (int)__float_as_uint(r.z);
      uint2 raw = *(const uint2*)(h2t + (size_t)src * IN_DIM + dd * 4);
      float2 p01 = __half22float2(*(const __half2*)&u01);
      float2 p23 = __half22float2(*(const __half2*)&u23);
      dn0 += p01.x; dn1 += p01.y; dn2 += p23.x; dn3 += p23.y;
      float2 h01 = __half22float2(*(const __half2*)&raw.x);
      float2 h23 = __half22float2(*(const __half2*)&raw.y);
      acc0 += p01.x * h01.x; acc1 += p01.y * h01.y;
      acc2 += p23.x * h23.x; acc3 += p23.y * h23.y;
    }

    dn0 += __shfl_xor(dn0, 32); dn1 += __shfl_xor(dn1, 32);
    dn2 += __shfl_xor(dn2, 32); dn3 += __shfl_xor(dn3, 32);
    acc0 += __shfl_xor(acc0, 32); acc1 += __shfl_xor(acc1, 32);
    acc2 += __shfl_xor(acc2, 32); acc3 += __shfl_xor(acc3, 32);

    if (half_ == 0) {
      float v = acc0 * (0.25f / (dn0 + 1e-16f)) + acc1 * (0.25f / (dn1 + 1e-16f))
              + acc2 * (0.25f / (dn2 + 1e-16f)) + acc3 * (0.25f / (dn3 + 1e-16f));
      out[(size_t)node * OUT_DIM + dd] = v + bias[dd];
    }
  }
}

extern "C" void kernel_launch(void* const* d_in, const int* in_sizes, int n_in,
                              void* d_out, int out_size, void* d_ws, size_t ws_size,
                              hipStream_t stream) {
  const float* x       = (const float*)d_in[0];
  const int*   ei      = (const int*)d_in[1];
  const float* eattr   = (const float*)d_in[2];
  const float* W_lin   = (const float*)d_in[3];
  const float* att_src = (const float*)d_in[4];
  const float* att_dst = (const float*)d_in[5];
  const float* bias    = (const float*)d_in[6];
  const float* W_edge  = (const float*)d_in[7];
  float* out = (float*)d_out;

  // ws: h2t(12.8MB) | rec(512*4224*16B = 34.6MB) | a_src | a_dst | gcursor
  __half* h2t  = (__half*)d_ws;
  float4* rec  = (float4*)(h2t + (size_t)N_NODES * IN_DIM);
  float* a_src = (float*)(rec + (size_t)NB * CAP);
  float* a_dst = a_src + (size_t)N_NODES * HEADS;
  unsigned int* gcursor = (unsigned int*)(a_dst + (size_t)N_NODES * HEADS);

  hipMemsetAsync(gcursor, 0, NB * sizeof(unsigned int), stream);

  k_gemm<<<(N_NODES + 31) / 32, 256, 0, stream>>>(
      x, W_lin, att_src, att_dst, h2t, a_src, a_dst);
  k_scatter3<<<(N_EDGES + SC_CHUNK - 1) / SC_CHUNK, 256, 0, stream>>>(
      ei, eattr, a_src, a_dst, W_edge, gcursor, rec);
  k_bagg<<<NB, 1024, 0, stream>>>(gcursor, rec, h2t, bias, out);
}